// Round 6
// baseline (463.257 us; speedup 1.0000x reference)
//
#include <hip/hip_runtime.h>
#include <hip/hip_bf16.h>

typedef __attribute__((ext_vector_type(8))) short bf16x8;
typedef __attribute__((ext_vector_type(8))) unsigned short u16x8;
typedef __attribute__((ext_vector_type(4))) float f32x4;

#define SEQ   8192
#define DEM   256
#define CHUNK 512
#define NTASKS 1088     // 8 XCD groups x 136 tasks

#define GLOAD_LDS16(g, l) \
  __builtin_amdgcn_global_load_lds((const __attribute__((address_space(1))) void*)(g), \
                                   (__attribute__((address_space(3))) void*)(l), 16, 0, 0)

static __device__ __forceinline__ unsigned short f2bf(float f) {
  union { float f; unsigned int u; } v; v.f = f;
  return (unsigned short)((v.u + 0x7fffu + ((v.u >> 16) & 1u)) >> 16);
}
static __device__ __forceinline__ float bf2f(unsigned short h) {
  union { unsigned int u; float f; } v; v.u = ((unsigned int)h) << 16;
  return v.f;
}

// ---- projections: qb[s][d] = (1/16)*sum_e x[s][e] Wq[d][e] (scale folded, exact pow2);
//      kb[s][d] = sum_e x[s][e] Wk[d][e]; vtb[d][s] = sum_e x[s][e] Wv[d][e]
__global__ __launch_bounds__(256) void proj_kernel(
    const float* __restrict__ x,  const float* __restrict__ Wq,
    const float* __restrict__ Wk, const float* __restrict__ Wv,
    unsigned short* __restrict__ qb, unsigned short* __restrict__ kb,
    unsigned short* __restrict__ vtb)
{
  const int m0 = blockIdx.x * 128;
  const int n0 = blockIdx.y * 128;
  const int which = blockIdx.z;
  const float* __restrict__ W = (which == 0) ? Wq : (which == 1) ? Wk : Wv;

  __shared__ unsigned short As[128 * 64];
  __shared__ unsigned short Bs[128 * 64];

  const int tid  = threadIdx.x;
  const int wave = tid >> 6, lane = tid & 63;
  const int wm = wave >> 1, wn = wave & 1;
  const int lr = lane & 15, lg = lane >> 4;

  f32x4 acc[4][4];
  #pragma unroll
  for (int i = 0; i < 4; i++)
    #pragma unroll
    for (int j = 0; j < 4; j++) acc[i][j] = (f32x4){0.f, 0.f, 0.f, 0.f};

  for (int k0 = 0; k0 < DEM; k0 += 64) {
    __syncthreads();
    #pragma unroll
    for (int p = 0; p < 8; p++) {
      int c   = p * 256 + tid;
      int row = c >> 4;
      int col = (c & 15) << 2;
      float4 fA = *reinterpret_cast<const float4*>(&x[(m0 + row) * DEM + k0 + col]);
      float4 fB = *reinterpret_cast<const float4*>(&W[(n0 + row) * DEM + k0 + col]);
      uint2 hA, hB;
      hA.x = f2bf(fA.x) | ((unsigned)f2bf(fA.y) << 16);
      hA.y = f2bf(fA.z) | ((unsigned)f2bf(fA.w) << 16);
      hB.x = f2bf(fB.x) | ((unsigned)f2bf(fB.y) << 16);
      hB.y = f2bf(fB.z) | ((unsigned)f2bf(fB.w) << 16);
      int byte = (row * 128 + (col << 1)) ^ ((row & 7) << 4);
      *reinterpret_cast<uint2*>(reinterpret_cast<char*>(As) + byte) = hA;
      *reinterpret_cast<uint2*>(reinterpret_cast<char*>(Bs) + byte) = hB;
    }
    __syncthreads();

    #pragma unroll
    for (int ks = 0; ks < 2; ks++) {
      bf16x8 a[4], b[4];
      #pragma unroll
      for (int mt = 0; mt < 4; mt++) {
        int row  = wm * 64 + mt * 16 + lr;
        int byte = (row * 128 + ks * 64 + lg * 16) ^ ((row & 7) << 4);
        a[mt] = *reinterpret_cast<const bf16x8*>(reinterpret_cast<const char*>(As) + byte);
      }
      #pragma unroll
      for (int nt = 0; nt < 4; nt++) {
        int row  = wn * 64 + nt * 16 + lr;
        int byte = (row * 128 + ks * 64 + lg * 16) ^ ((row & 7) << 4);
        b[nt] = *reinterpret_cast<const bf16x8*>(reinterpret_cast<const char*>(Bs) + byte);
      }
      #pragma unroll
      for (int mt = 0; mt < 4; mt++)
        #pragma unroll
        for (int nt = 0; nt < 4; nt++)
          acc[mt][nt] = __builtin_amdgcn_mfma_f32_16x16x32_bf16(a[mt], b[nt], acc[mt][nt], 0, 0, 0);
    }
  }

  const float osc = (which == 0) ? 0.0625f : 1.0f;   // fold 1/sqrt(256) into Q
  #pragma unroll
  for (int mt = 0; mt < 4; mt++)
    #pragma unroll
    for (int nt = 0; nt < 4; nt++)
      #pragma unroll
      for (int r = 0; r < 4; r++) {
        int row = m0 + wm * 64 + mt * 16 + lg * 4 + r;
        int col = n0 + wn * 64 + nt * 16 + lr;
        unsigned short h = f2bf(acc[mt][nt][r] * osc);
        if (which == 0)      qb[row * DEM + col]  = h;
        else if (which == 1) kb[row * DEM + col]  = h;
        else                 vtb[(size_t)col * SEQ + row] = h;
      }
}

// ---- attention: task = (qtile of 64 rows, kv chunk <=512), XCD-grouped by chunk.
// 4 waves x 16 q-rows. K LDS double-buffered (gload_lds w16). Swapped QK^T:
// mfma(K,Q) puts a full P-row per lane (q=lr) -> scalar online-softmax state,
// 2-round cross-lane reduce, b64 P writes / b128 P reads (conflict-free-ish).
__global__ __launch_bounds__(256, 2) void attn_kernel(
    const unsigned short* __restrict__ qb, const unsigned short* __restrict__ kb,
    const unsigned short* __restrict__ vtb,
    unsigned short* __restrict__ pOb, float* __restrict__ ml)
{
  __shared__ char lds[73728];
  char* Ks = lds;             // 2 x 32KB K tiles [64 rows x 512B], swizzled
  char* Ps = lds + 65536;     // 4 waves x 2KB P [16 q-rows x 128B], swizzled

  // ---- task decode: XCD x = blockIdx%8 handles chunks {x, 15-x} (136 tasks each)
  const int p = (int)blockIdx.x;
  const int x = p & 7;
  const int s = p >> 3;
  const int n1 = 128 - 8 * x;          // tasks in chunk x (q = 8x..127), q descending
  int c, q;
  if (s < n1) { c = x;      q = 127 - s; }
  else        { c = 15 - x; q = 127 - (s - n1); }
  // storage index (order-independent): base(q) + c
  const int a_ = q >> 3, b_ = q & 7;
  const int t_store = q + 4 * a_ * (a_ - 1) + b_ * a_ + c;

  const int kv_lo = c * CHUNK;
  const int kv_hi_blk = min(kv_lo + CHUNK, (q + 1) * 64);

  const int tid = threadIdx.x;
  const int wave = tid >> 6, lane = tid & 63;
  const int lr = lane & 15, lg = lane >> 4;
  const int qrow = q * 64 + wave * 16;
  const int kv_hi_w = min(kv_hi_blk, ((qrow + 16 + 63) >> 6) << 6);
  char* pb = Ps + wave * 2048;

  // ---- Q fragments hoisted for the whole kernel (B-operand: n=lr, k contiguous)
  bf16x8 qf[8];
  {
    const unsigned short* qp = qb + (size_t)(qrow + lr) * DEM + lg * 8;
    #pragma unroll
    for (int ks = 0; ks < 8; ks++) qf[ks] = *reinterpret_cast<const bf16x8*>(qp + ks * 32);
  }

  f32x4 o[16];
  #pragma unroll
  for (int d = 0; d < 16; d++) o[d] = (f32x4){0.f, 0.f, 0.f, 0.f};
  float m_run = -3.0e38f, l_run = 0.f;    // per-lane: q-row = qrow + lr

  // ---- prologue: stage K tile 0 into buf 0
  #pragma unroll
  for (int i = 0; i < 8; i++) {
    int sl = i * 4096 + tid * 16;
    int row = sl >> 9;
    int inrow = (sl & 511) ^ ((row & 7) << 4);
    GLOAD_LDS16((const char*)kb + (((size_t)(kv_lo + row)) << 9) + inrow,
                Ks + i * 4096 + (wave << 10));
  }
  __syncthreads();

  const int nsteps = (kv_hi_blk - kv_lo) >> 6;
  for (int st = 0; st < nsteps; st++) {
    const int kv0 = kv_lo + (st << 6);
    const int buf = st & 1;
    // ---- issue async stage of K(t+1) into buf^1 (no VGPR cost)
    if (st + 1 < nsteps) {
      #pragma unroll
      for (int i = 0; i < 8; i++) {
        int sl = i * 4096 + tid * 16;
        int row = sl >> 9;
        int inrow = (sl & 511) ^ ((row & 7) << 4);
        GLOAD_LDS16((const char*)kb + (((size_t)(kv0 + 64 + row)) << 9) + inrow,
                    Ks + (buf ^ 1) * 32768 + i * 4096 + (wave << 10));
      }
    }

    const bool act = kv0 < kv_hi_w;
    if (act) {
      // ---- early-issue V first-half (T14)
      bf16x8 va[16], vb[16];
      #pragma unroll
      for (int d = 0; d < 16; d++)
        va[d] = *reinterpret_cast<const bf16x8*>(vtb + (size_t)(d * 16 + lr) * SEQ + kv0 + lg * 8);

      // ---- QK^T swapped: sc[nt] = K_tile(nt) x Q  -> lane holds q=lr, kv=kv0+16nt+4lg+r
      f32x4 sc[4];
      #pragma unroll
      for (int nt = 0; nt < 4; nt++) sc[nt] = (f32x4){0.f, 0.f, 0.f, 0.f};
      const char* kbase = Ks + buf * 32768;
      __builtin_amdgcn_s_setprio(1);
      #pragma unroll
      for (int ks = 0; ks < 8; ks++)
        #pragma unroll
        for (int nt = 0; nt < 4; nt++) {
          int krow = nt * 16 + lr;
          int byte = (krow * 512 + ks * 64 + lg * 16) ^ ((krow & 7) << 4);
          bf16x8 kf = *reinterpret_cast<const bf16x8*>(kbase + byte);
          sc[nt] = __builtin_amdgcn_mfma_f32_16x16x32_bf16(kf, qf[ks], sc[nt], 0, 0, 0);
        }
      __builtin_amdgcn_s_setprio(0);

      // ---- issue V second-half while softmax runs
      #pragma unroll
      for (int d = 0; d < 16; d++)
        vb[d] = *reinterpret_cast<const bf16x8*>(vtb + (size_t)(d * 16 + lr) * SEQ + kv0 + 32 + lg * 8);

      // ---- online softmax, per-lane row (q = qrow + lr)
      const int qg = qrow + lr;
      const bool diag = (kv0 + 63 > qrow);
      float sm[16];
      #pragma unroll
      for (int nt = 0; nt < 4; nt++)
        #pragma unroll
        for (int r = 0; r < 4; r++) {
          float v = sc[nt][r];
          if (diag && (kv0 + nt * 16 + lg * 4 + r > qg)) v = -3.0e38f;
          sm[nt * 4 + r] = v;
        }
      float mx = sm[0];
      #pragma unroll
      for (int j = 1; j < 16; j++) mx = fmaxf(mx, sm[j]);
      mx = fmaxf(mx, __shfl_xor(mx, 16));
      mx = fmaxf(mx, __shfl_xor(mx, 32));
      const float mnew = fmaxf(m_run, mx);
      const float cr = __expf(m_run - mnew);
      float e[16], sum = 0.f;
      #pragma unroll
      for (int j = 0; j < 16; j++) { e[j] = __expf(sm[j] - mnew); sum += e[j]; }
      sum += __shfl_xor(sum, 16);
      sum += __shfl_xor(sum, 32);
      m_run = mnew;
      l_run = l_run * cr + sum;

      // ---- P -> LDS: per nt one b64 (4 consecutive kv), swizzled
      #pragma unroll
      for (int nt = 0; nt < 4; nt++) {
        uint2 w;
        w.x = (unsigned)f2bf(e[nt * 4 + 0]) | ((unsigned)f2bf(e[nt * 4 + 1]) << 16);
        w.y = (unsigned)f2bf(e[nt * 4 + 2]) | ((unsigned)f2bf(e[nt * 4 + 3]) << 16);
        *reinterpret_cast<uint2*>(pb + ((lr * 128 + nt * 32 + lg * 8) ^ ((lr & 7) << 4))) = w;
      }

      // ---- corr broadcast to O-rows (o row q = qrow + lg*4 + r lives on lane lr'=lg*4+r)
      float cf[4];
      #pragma unroll
      for (int r = 0; r < 4; r++) cf[r] = __shfl(cr, lg * 4 + r);
      #pragma unroll
      for (int d = 0; d < 16; d++)
        #pragma unroll
        for (int r = 0; r < 4; r++) o[d][r] *= cf[r];

      // ---- P read (A-operand: m=lr=q, k = 8lg..8lg+7) + PV
      bf16x8 pf0 = *reinterpret_cast<const bf16x8*>(pb + ((lr * 128 +      lg * 16) ^ ((lr & 7) << 4)));
      bf16x8 pf1 = *reinterpret_cast<const bf16x8*>(pb + ((lr * 128 + 64 + lg * 16) ^ ((lr & 7) << 4)));
      __builtin_amdgcn_s_setprio(1);
      #pragma unroll
      for (int d = 0; d < 16; d++) {
        o[d] = __builtin_amdgcn_mfma_f32_16x16x32_bf16(pf0, va[d], o[d], 0, 0, 0);
        o[d] = __builtin_amdgcn_mfma_f32_16x16x32_bf16(pf1, vb[d], o[d], 0, 0, 0);
      }
      __builtin_amdgcn_s_setprio(0);
    }
    __syncthreads();   // stage(t+1) drained; K buf safe to flip
  }

  // ---- write partials (bf16 O unnormalized, f32 m/l)
  const size_t obase = (size_t)t_store * (64 * 256);
  #pragma unroll
  for (int d = 0; d < 16; d++)
    #pragma unroll
    for (int r = 0; r < 4; r++) {
      const int row_l = wave * 16 + lg * 4 + r;
      pOb[obase + (size_t)row_l * 256 + d * 16 + lr] = f2bf(o[d][r]);
    }
  if (lg == 0) {
    const int row_l = wave * 16 + lr;
    ml[(size_t)t_store * 128 + row_l * 2]     = m_run;
    ml[(size_t)t_store * 128 + row_l * 2 + 1] = l_run;
  }
}

// ---- merge partials
__global__ __launch_bounds__(256) void merge_kernel(
    const unsigned short* __restrict__ pOb, const float* __restrict__ ml,
    float* __restrict__ out)
{
  const int tid = threadIdx.x;
  const int row = blockIdx.x * 32 + (tid >> 3);
  const int c0  = (tid & 7) * 32;
  const int q = row >> 6;              // 64-row qtile
  const int a = q >> 3, b = q & 7;
  const int n = a + 1;                 // chunks for this qtile
  const int base = q + 4 * a * (a - 1) + b * a;
  const int lrow = row & 63;

  float M = -3.0e38f;
  for (int i = 0; i < n; i++)
    M = fmaxf(M, ml[(size_t)(base + i) * 128 + lrow * 2]);

  float L = 0.f;
  float acc[32];
  #pragma unroll
  for (int j = 0; j < 32; j++) acc[j] = 0.f;

  for (int i = 0; i < n; i++) {
    const float mi = ml[(size_t)(base + i) * 128 + lrow * 2];
    const float li = ml[(size_t)(base + i) * 128 + lrow * 2 + 1];
    const float fi = __expf(mi - M);
    L += li * fi;
    const unsigned short* src = pOb + (size_t)(base + i) * (64 * 256) + (size_t)lrow * 256 + c0;
    #pragma unroll
    for (int v = 0; v < 4; v++) {
      u16x8 u = *reinterpret_cast<const u16x8*>(src + v * 8);
      #pragma unroll
      for (int j = 0; j < 8; j++) acc[v * 8 + j] += bf2f((unsigned short)u[j]) * fi;
    }
  }
  const float inv = 1.f / L;
  #pragma unroll
  for (int v = 0; v < 8; v++) {
    float4 w;
    w.x = acc[v * 4 + 0] * inv; w.y = acc[v * 4 + 1] * inv;
    w.z = acc[v * 4 + 2] * inv; w.w = acc[v * 4 + 3] * inv;
    *reinterpret_cast<float4*>(&out[(size_t)row * 256 + c0 + v * 4]) = w;
  }
}

extern "C" void kernel_launch(void* const* d_in, const int* in_sizes, int n_in,
                              void* d_out, int out_size, void* d_ws, size_t ws_size,
                              hipStream_t stream)
{
  const float* x  = (const float*)d_in[0];
  const float* Wq = (const float*)d_in[1];
  const float* Wk = (const float*)d_in[2];
  const float* Wv = (const float*)d_in[3];

  char* ws = (char*)d_ws;
  unsigned short* qb  = (unsigned short*)ws;                              // 4 MB
  unsigned short* kb  = (unsigned short*)(ws + (size_t)4  * 1024 * 1024); // 4 MB
  unsigned short* vtb = (unsigned short*)(ws + (size_t)8  * 1024 * 1024); // 4 MB
  float*          ml  = (float*)         (ws + (size_t)12 * 1024 * 1024); // 557 KB
  unsigned short* pOb = (unsigned short*)(ws + (size_t)13 * 1024 * 1024); // 35.7 MB

  proj_kernel<<<dim3(64, 2, 3), 256, 0, stream>>>(x, Wq, Wk, Wv, qb, kb, vtb);
  attn_kernel<<<dim3(NTASKS), 256, 0, stream>>>(qb, kb, vtb, pOb, ml);
  merge_kernel<<<dim3(SEQ / 32), 256, 0, stream>>>(pOb, ml, (float*)d_out);
}

// Round 7
// 125.716 us; speedup vs baseline: 3.6849x; 3.6849x over previous
//
#include <hip/hip_runtime.h>
#include <hip/hip_bf16.h>

typedef __attribute__((ext_vector_type(8))) short bf16x8;
typedef __attribute__((ext_vector_type(8))) unsigned short u16x8;
typedef __attribute__((ext_vector_type(4))) float f32x4;

#define SEQ   8192
#define DEM   256
#define CHUNK 512
#define NTASKS 544      // sum over 64 qtiles (128 rows) of (q>>2)+1

#define GLOAD_LDS16(g, l) \
  __builtin_amdgcn_global_load_lds((const __attribute__((address_space(1))) void*)(g), \
                                   (__attribute__((address_space(3))) void*)(l), 16, 0, 0)

static __device__ __forceinline__ unsigned short f2bf(float f) {
  union { float f; unsigned int u; } v; v.f = f;
  return (unsigned short)((v.u + 0x7fffu + ((v.u >> 16) & 1u)) >> 16);
}
static __device__ __forceinline__ float bf2f(unsigned short h) {
  union { unsigned int u; float f; } v; v.u = ((unsigned int)h) << 16;
  return v.f;
}

// ---- projections: qb[s][d] = (1/16)*sum_e x[s][e] Wq[d][e] (scale folded, exact pow2);
//      kb[s][d] = sum_e x[s][e] Wk[d][e]; vtb[d][s] = sum_e x[s][e] Wv[d][e]
__global__ __launch_bounds__(256) void proj_kernel(
    const float* __restrict__ x,  const float* __restrict__ Wq,
    const float* __restrict__ Wk, const float* __restrict__ Wv,
    unsigned short* __restrict__ qb, unsigned short* __restrict__ kb,
    unsigned short* __restrict__ vtb)
{
  const int m0 = blockIdx.x * 128;
  const int n0 = blockIdx.y * 128;
  const int which = blockIdx.z;
  const float* __restrict__ W = (which == 0) ? Wq : (which == 1) ? Wk : Wv;

  __shared__ unsigned short As[128 * 64];
  __shared__ unsigned short Bs[128 * 64];

  const int tid  = threadIdx.x;
  const int wave = tid >> 6, lane = tid & 63;
  const int wm = wave >> 1, wn = wave & 1;
  const int lr = lane & 15, lg = lane >> 4;

  f32x4 acc[4][4];
  #pragma unroll
  for (int i = 0; i < 4; i++)
    #pragma unroll
    for (int j = 0; j < 4; j++) acc[i][j] = (f32x4){0.f, 0.f, 0.f, 0.f};

  for (int k0 = 0; k0 < DEM; k0 += 64) {
    __syncthreads();
    #pragma unroll
    for (int p = 0; p < 8; p++) {
      int c   = p * 256 + tid;
      int row = c >> 4;
      int col = (c & 15) << 2;
      float4 fA = *reinterpret_cast<const float4*>(&x[(m0 + row) * DEM + k0 + col]);
      float4 fB = *reinterpret_cast<const float4*>(&W[(n0 + row) * DEM + k0 + col]);
      uint2 hA, hB;
      hA.x = f2bf(fA.x) | ((unsigned)f2bf(fA.y) << 16);
      hA.y = f2bf(fA.z) | ((unsigned)f2bf(fA.w) << 16);
      hB.x = f2bf(fB.x) | ((unsigned)f2bf(fB.y) << 16);
      hB.y = f2bf(fB.z) | ((unsigned)f2bf(fB.w) << 16);
      int byte = (row * 128 + (col << 1)) ^ ((row & 7) << 4);
      *reinterpret_cast<uint2*>(reinterpret_cast<char*>(As) + byte) = hA;
      *reinterpret_cast<uint2*>(reinterpret_cast<char*>(Bs) + byte) = hB;
    }
    __syncthreads();

    #pragma unroll
    for (int ks = 0; ks < 2; ks++) {
      bf16x8 a[4], b[4];
      #pragma unroll
      for (int mt = 0; mt < 4; mt++) {
        int row  = wm * 64 + mt * 16 + lr;
        int byte = (row * 128 + ks * 64 + lg * 16) ^ ((row & 7) << 4);
        a[mt] = *reinterpret_cast<const bf16x8*>(reinterpret_cast<const char*>(As) + byte);
      }
      #pragma unroll
      for (int nt = 0; nt < 4; nt++) {
        int row  = wn * 64 + nt * 16 + lr;
        int byte = (row * 128 + ks * 64 + lg * 16) ^ ((row & 7) << 4);
        b[nt] = *reinterpret_cast<const bf16x8*>(reinterpret_cast<const char*>(Bs) + byte);
      }
      #pragma unroll
      for (int mt = 0; mt < 4; mt++)
        #pragma unroll
        for (int nt = 0; nt < 4; nt++)
          acc[mt][nt] = __builtin_amdgcn_mfma_f32_16x16x32_bf16(a[mt], b[nt], acc[mt][nt], 0, 0, 0);
    }
  }

  const float osc = (which == 0) ? 0.0625f : 1.0f;   // fold 1/sqrt(256) into Q
  #pragma unroll
  for (int mt = 0; mt < 4; mt++)
    #pragma unroll
    for (int nt = 0; nt < 4; nt++)
      #pragma unroll
      for (int r = 0; r < 4; r++) {
        int row = m0 + wm * 64 + mt * 16 + lg * 4 + r;
        int col = n0 + wn * 64 + nt * 16 + lr;
        unsigned short h = f2bf(acc[mt][nt][r] * osc);
        if (which == 0)      qb[row * DEM + col]  = h;
        else if (which == 1) kb[row * DEM + col]  = h;
        else                 vtb[(size_t)col * SEQ + row] = h;
      }
}

// ---- attention: task = (qtile of 128 rows, kv chunk <=512). 8 waves x 16 q-rows.
// K AND V double-buffered in LDS via global_load_lds w16 (zero VGPR staging),
// one barrier per 64-kv step. Swapped QK^T -> per-lane scalar softmax state.
__global__ __launch_bounds__(512, 2) void attn_kernel(
    const unsigned short* __restrict__ qb, const unsigned short* __restrict__ kb,
    const unsigned short* __restrict__ vtb,
    unsigned short* __restrict__ pOb, float* __restrict__ ml)
{
  __shared__ char lds[147456];
  char* Ks = lds;               // 2 x 32KB K tiles [64 rows x 512B], swizzled
  char* Vs = lds + 65536;       // 2 x 32KB Vt tiles [256 d-rows x 128B], swizzled
  char* Ps = lds + 131072;      // 8 waves x 2KB P [16 q x 128B], swizzled

  // ---- task decode: nch(q) = (q>>2)+1, q = qtile 0..63
  const int t = NTASKS - 1 - (int)blockIdx.x;   // largest q first
  int q = 0, s = 0;
  for (;;) { int n = (q >> 2) + 1; if (t < s + n) break; s += n; ++q; }
  const int c = t - s;
  const int kv_lo = c * CHUNK;
  const int kv_hi_blk = min(kv_lo + CHUNK, (q + 1) * 128);

  const int tid = threadIdx.x;
  const int wave = tid >> 6, lane = tid & 63;
  const int lr = lane & 15, lg = lane >> 4;
  const int qrow = q * 128 + wave * 16;
  const int kv_hi_w = min(kv_hi_blk, ((qrow + 16 + 63) >> 6) << 6);
  char* pb = Ps + wave * 2048;

  // ---- Q fragments hoisted (B-operand: n=lr -> q-row qrow+lr, k = lg*8..)
  bf16x8 qf[8];
  {
    const unsigned short* qp = qb + (size_t)(qrow + lr) * DEM + lg * 8;
    #pragma unroll
    for (int ks = 0; ks < 8; ks++) qf[ks] = *reinterpret_cast<const bf16x8*>(qp + ks * 32);
  }

  f32x4 o[16];
  #pragma unroll
  for (int d = 0; d < 16; d++) o[d] = (f32x4){0.f, 0.f, 0.f, 0.f};
  float m_run = -3.0e38f, l_run = 0.f;    // per-lane: q-row = qrow + lr

  // ---- prologue: stage K(0), V(0) into buf 0
  #pragma unroll
  for (int i = 0; i < 4; i++) {
    int sl = i * 8192 + (wave << 10) + (lane << 4);
    int krow = sl >> 9;
    int kin  = (sl & 511) ^ ((krow & 7) << 4);
    GLOAD_LDS16((const char*)kb + (((size_t)(kv_lo + krow)) << 9) + kin,
                Ks + i * 8192 + (wave << 10));
    int vrow = sl >> 7;
    int vin  = (sl & 127) ^ ((vrow & 7) << 4);
    GLOAD_LDS16((const char*)vtb + ((size_t)vrow * SEQ + kv_lo) * 2 + vin,
                Vs + i * 8192 + (wave << 10));
  }
  __syncthreads();

  const int nsteps = (kv_hi_blk - kv_lo) >> 6;
  for (int st = 0; st < nsteps; st++) {
    const int kv0 = kv_lo + (st << 6);
    const int buf = st & 1;
    // ---- issue async stage of K(t+1), V(t+1) into buf^1 (no VGPR cost)
    if (st + 1 < nsteps) {
      #pragma unroll
      for (int i = 0; i < 4; i++) {
        int sl = i * 8192 + (wave << 10) + (lane << 4);
        int krow = sl >> 9;
        int kin  = (sl & 511) ^ ((krow & 7) << 4);
        GLOAD_LDS16((const char*)kb + (((size_t)(kv0 + 64 + krow)) << 9) + kin,
                    Ks + (buf ^ 1) * 32768 + i * 8192 + (wave << 10));
        int vrow = sl >> 7;
        int vin  = (sl & 127) ^ ((vrow & 7) << 4);
        GLOAD_LDS16((const char*)vtb + ((size_t)vrow * SEQ + kv0 + 64) * 2 + vin,
                    Vs + (buf ^ 1) * 32768 + i * 8192 + (wave << 10));
      }
    }

    const bool act = kv0 < kv_hi_w;
    if (act) {
      // ---- QK^T swapped: sc[nt] = K_tile(nt) x Q; lane holds q=lr, kv=nt*16+lg*4+r
      f32x4 sc[4];
      #pragma unroll
      for (int nt = 0; nt < 4; nt++) sc[nt] = (f32x4){0.f, 0.f, 0.f, 0.f};
      const char* kbase = Ks + buf * 32768;
      __builtin_amdgcn_s_setprio(1);
      #pragma unroll
      for (int ks = 0; ks < 8; ks++)
        #pragma unroll
        for (int nt = 0; nt < 4; nt++) {
          int krow = nt * 16 + lr;
          int byte = krow * 512 + ((ks * 64 + lg * 16) ^ ((krow & 7) << 4));
          bf16x8 kf = *reinterpret_cast<const bf16x8*>(kbase + byte);
          sc[nt] = __builtin_amdgcn_mfma_f32_16x16x32_bf16(kf, qf[ks], sc[nt], 0, 0, 0);
        }
      __builtin_amdgcn_s_setprio(0);

      // ---- online softmax, per-lane row (q = qrow + lr)
      const int qg = qrow + lr;
      const bool diag = (kv0 + 63 > qrow);
      float sm[16];
      #pragma unroll
      for (int nt = 0; nt < 4; nt++)
        #pragma unroll
        for (int r = 0; r < 4; r++) {
          float v = sc[nt][r];
          if (diag && (kv0 + nt * 16 + lg * 4 + r > qg)) v = -3.0e38f;
          sm[nt * 4 + r] = v;
        }
      float mx = sm[0];
      #pragma unroll
      for (int j = 1; j < 16; j++) mx = fmaxf(mx, sm[j]);
      mx = fmaxf(mx, __shfl_xor(mx, 16));
      mx = fmaxf(mx, __shfl_xor(mx, 32));
      const float mnew = fmaxf(m_run, mx);
      const float cr = __expf(m_run - mnew);
      float e[16], sum = 0.f;
      #pragma unroll
      for (int j = 0; j < 16; j++) { e[j] = __expf(sm[j] - mnew); sum += e[j]; }
      sum += __shfl_xor(sum, 16);
      sum += __shfl_xor(sum, 32);
      m_run = mnew;
      l_run = l_run * cr + sum;

      // ---- P -> LDS: per nt one b64 (4 consecutive kv), swizzled
      #pragma unroll
      for (int nt = 0; nt < 4; nt++) {
        uint2 w;
        w.x = (unsigned)f2bf(e[nt * 4 + 0]) | ((unsigned)f2bf(e[nt * 4 + 1]) << 16);
        w.y = (unsigned)f2bf(e[nt * 4 + 2]) | ((unsigned)f2bf(e[nt * 4 + 3]) << 16);
        *reinterpret_cast<uint2*>(pb + (lr * 128 + ((nt * 32 + lg * 8) ^ ((lr & 7) << 4)))) = w;
      }

      // ---- corr broadcast to O-rows (o reg r row = qrow + lg*4 + r, cr on lane lg*4+r)
      float cf[4];
      #pragma unroll
      for (int r = 0; r < 4; r++) cf[r] = __shfl(cr, lg * 4 + r);
      #pragma unroll
      for (int d = 0; d < 16; d++)
        #pragma unroll
        for (int r = 0; r < 4; r++) o[d][r] *= cf[r];

      // ---- P read (A-operand: m=lr=q, k=lg*8..) + PV from LDS V
      bf16x8 pf0 = *reinterpret_cast<const bf16x8*>(pb + (lr * 128 + ((lg * 16)      ^ ((lr & 7) << 4))));
      bf16x8 pf1 = *reinterpret_cast<const bf16x8*>(pb + (lr * 128 + ((64 + lg * 16) ^ ((lr & 7) << 4))));
      const char* vbase = Vs + buf * 32768;
      __builtin_amdgcn_s_setprio(1);
      #pragma unroll
      for (int d = 0; d < 16; d++) {
        const int vrow = d * 16 + lr;
        const int vswz = (vrow & 7) << 4;
        bf16x8 v0 = *reinterpret_cast<const bf16x8*>(vbase + vrow * 128 + ((lg * 16)      ^ vswz));
        bf16x8 v1 = *reinterpret_cast<const bf16x8*>(vbase + vrow * 128 + ((64 + lg * 16) ^ vswz));
        o[d] = __builtin_amdgcn_mfma_f32_16x16x32_bf16(pf0, v0, o[d], 0, 0, 0);
        o[d] = __builtin_amdgcn_mfma_f32_16x16x32_bf16(pf1, v1, o[d], 0, 0, 0);
      }
      __builtin_amdgcn_s_setprio(0);
    }
    __syncthreads();   // drains stage(t+1) (vmcnt0 at barrier); buffers safe to flip
  }

  // ---- write partials (bf16 O unnormalized, f32 m/l)
  const size_t obase = (size_t)t * (128 * 256);
  #pragma unroll
  for (int d = 0; d < 16; d++)
    #pragma unroll
    for (int r = 0; r < 4; r++) {
      const int row_l = wave * 16 + lg * 4 + r;
      pOb[obase + (size_t)row_l * 256 + d * 16 + lr] = f2bf(o[d][r]);
    }
  if (lg == 0) {
    const int row_l = wave * 16 + lr;
    ml[(size_t)t * 256 + row_l * 2]     = m_run;
    ml[(size_t)t * 256 + row_l * 2 + 1] = l_run;
  }
}

// ---- merge partials
__global__ __launch_bounds__(256) void merge_kernel(
    const unsigned short* __restrict__ pOb, const float* __restrict__ ml,
    float* __restrict__ out)
{
  const int tid = threadIdx.x;
  const int row = blockIdx.x * 32 + (tid >> 3);
  const int c0  = (tid & 7) * 32;
  const int q = row >> 7;              // 128-row qtile, 0..63
  const int a = q >> 2, b = q & 3;
  const int n = a + 1;                 // chunks for this qtile
  const int base = (2 * a + b) * (a + 1);
  const int lrow = row & 127;

  float M = -3.0e38f;
  for (int i = 0; i < n; i++)
    M = fmaxf(M, ml[(size_t)(base + i) * 256 + lrow * 2]);

  float L = 0.f;
  float acc[32];
  #pragma unroll
  for (int j = 0; j < 32; j++) acc[j] = 0.f;

  for (int i = 0; i < n; i++) {
    const float mi = ml[(size_t)(base + i) * 256 + lrow * 2];
    const float li = ml[(size_t)(base + i) * 256 + lrow * 2 + 1];
    const float fi = __expf(mi - M);
    L += li * fi;
    const unsigned short* src = pOb + (size_t)(base + i) * (128 * 256) + (size_t)lrow * 256 + c0;
    #pragma unroll
    for (int v = 0; v < 4; v++) {
      u16x8 u = *reinterpret_cast<const u16x8*>(src + v * 8);
      #pragma unroll
      for (int j = 0; j < 8; j++) acc[v * 8 + j] += bf2f((unsigned short)u[j]) * fi;
    }
  }
  const float inv = 1.f / L;
  #pragma unroll
  for (int v = 0; v < 8; v++) {
    float4 w;
    w.x = acc[v * 4 + 0] * inv; w.y = acc[v * 4 + 1] * inv;
    w.z = acc[v * 4 + 2] * inv; w.w = acc[v * 4 + 3] * inv;
    *reinterpret_cast<float4*>(&out[(size_t)row * 256 + c0 + v * 4]) = w;
  }
}

extern "C" void kernel_launch(void* const* d_in, const int* in_sizes, int n_in,
                              void* d_out, int out_size, void* d_ws, size_t ws_size,
                              hipStream_t stream)
{
  const float* x  = (const float*)d_in[0];
  const float* Wq = (const float*)d_in[1];
  const float* Wk = (const float*)d_in[2];
  const float* Wv = (const float*)d_in[3];

  char* ws = (char*)d_ws;
  unsigned short* qb  = (unsigned short*)ws;                              // 4 MB
  unsigned short* kb  = (unsigned short*)(ws + (size_t)4  * 1024 * 1024); // 4 MB
  unsigned short* vtb = (unsigned short*)(ws + (size_t)8  * 1024 * 1024); // 4 MB
  float*          ml  = (float*)         (ws + (size_t)12 * 1024 * 1024); // 544 KB
  unsigned short* pOb = (unsigned short*)(ws + (size_t)13 * 1024 * 1024); // 17.8 MB

  proj_kernel<<<dim3(64, 2, 3), 256, 0, stream>>>(x, Wq, Wk, Wv, qb, kb, vtb);
  attn_kernel<<<dim3(NTASKS), 512, 0, stream>>>(qb, kb, vtb, pOb, ml);
  merge_kernel<<<dim3(SEQ / 32), 256, 0, stream>>>(pOb, ml, (float*)d_out);
}